// Round 6
// baseline (474.211 us; speedup 1.0000x reference)
//
#include <hip/hip_runtime.h>

#define NEG_SLOPE 0.2f
#define BK_LOG 9
#define BK_NODES (1 << BK_LOG)       // 512 nodes per bucket
#define TILE_EPT 24
#define TILE_E (256 * TILE_EPT)      // 6144 edges per partition tile

typedef __attribute__((ext_vector_type(8))) short bf8_t;   // 8 bf16 (4 VGPRs)
typedef __attribute__((ext_vector_type(4))) float f32x4;

__device__ __forceinline__ float leaky(float v) {
    return fmaxf(v, 0.0f) + NEG_SLOPE * fminf(v, 0.0f);
}

// fp32 -> bf16 (RNE) bit tricks; inputs are finite (no NaN handling needed)
__device__ __forceinline__ unsigned short f2bf(float f) {
    unsigned u = __float_as_uint(f);
    u += 0x7fffu + ((u >> 16) & 1u);
    return (unsigned short)(u >> 16);
}
__device__ __forceinline__ float bf2f(unsigned short h) {
    return __uint_as_float(((unsigned)h) << 16);
}

// exclusive scan of one value per thread across a 256-thread block
__device__ __forceinline__ int scan256_excl(int v, int* tmp) {
    int t = threadIdx.x;
    tmp[t] = v;
    __syncthreads();
    for (int d = 1; d < 256; d <<= 1) {
        int x = (t >= d) ? tmp[t - d] : 0;
        __syncthreads();
        tmp[t] += x;
        __syncthreads();
    }
    int r = tmp[t] - v;
    __syncthreads();
    return r;
}

// ---------------- edge partition (counting sort by dst-bucket) ----------------

__global__ __launch_bounds__(256) void k_bzero(int* __restrict__ bcnt) {
    bcnt[threadIdx.x] = 0;
}

__global__ __launch_bounds__(256) void k_bcount(const int* __restrict__ edst,
                                                int* __restrict__ bcnt, int E) {
    __shared__ int th[256];
    int t = threadIdx.x;
    th[t] = 0;
    __syncthreads();
    int base = blockIdx.x * TILE_E;
#pragma unroll
    for (int k = 0; k < TILE_EPT; ++k) {
        int e = base + t + k * 256;
        if (e < E) atomicAdd(&th[edst[e] >> BK_LOG], 1);
    }
    __syncthreads();
    if (th[t]) atomicAdd(&bcnt[t], th[t]);
}

__global__ __launch_bounds__(256) void k_bscan(const int* __restrict__ bcnt,
                                               int* __restrict__ bbase,
                                               int* __restrict__ bcur,
                                               int* __restrict__ off, int N, int E) {
    __shared__ int tmp[256];
    int t = threadIdx.x;
    int ex = scan256_excl(bcnt[t], tmp);
    bbase[t] = ex;
    bcur[t]  = ex;
    if (t == 0) { bbase[256] = E; off[N] = E; }
}

__global__ __launch_bounds__(256) void k_bplace(const int* __restrict__ esrc,
                                                const int* __restrict__ edst,
                                                int* __restrict__ bcur,
                                                int2* __restrict__ pairs, int E) {
    __shared__ int2 sp[TILE_E];
    __shared__ int th[256], tx[256], rb[256], tmp[256];
    int t = threadIdx.x;
    th[t] = 0;
    __syncthreads();
    int base = blockIdx.x * TILE_E;
    int tot  = min(TILE_E, E - base);
#pragma unroll
    for (int k = 0; k < TILE_EPT; ++k) {
        int e = base + t + k * 256;
        if (e < E) atomicAdd(&th[edst[e] >> BK_LOG], 1);
    }
    __syncthreads();
    int cnt = th[t];
    tx[t] = scan256_excl(cnt, tmp);
    rb[t] = atomicAdd(&bcur[t], cnt);
    th[t] = 0;
    __syncthreads();
#pragma unroll
    for (int k = 0; k < TILE_EPT; ++k) {
        int e = base + t + k * 256;
        if (e < E) {
            int s = esrc[e], d = edst[e];
            int b = d >> BK_LOG;
            int r = atomicAdd(&th[b], 1);
            sp[tx[b] + r] = make_int2(s, d);
        }
    }
    __syncthreads();
    for (int i = t; i < tot; i += 256) {
        int2 p = sp[i];
        int  b = p.y >> BK_LOG;
        pairs[rb[b] + (i - tx[b])] = p;
    }
}

__global__ __launch_bounds__(256) void k_csr(const int* __restrict__ bbase,
                                             const int2* __restrict__ pairs,
                                             int* __restrict__ off,
                                             int* __restrict__ csr, int N) {
    __shared__ int lh[BK_NODES], lx[BK_NODES];
    int b = blockIdx.x, t = threadIdx.x;
    int lo = bbase[b], hi = bbase[b + 1];
    int node0 = b << BK_LOG;
    lh[t] = 0; lh[t + 256] = 0;
    __syncthreads();
    for (int j = lo + t; j < hi; j += 256)
        atomicAdd(&lh[pairs[j].y - node0], 1);
    __syncthreads();
    lx[t] = lh[t]; lx[t + 256] = lh[t + 256];
    __syncthreads();
    for (int d = 1; d < BK_NODES; d <<= 1) {
        int i1 = t + 256;
        int x0 = (t  >= d) ? lx[t  - d] : 0;
        int x1 = (i1 >= d) ? lx[i1 - d] : 0;
        __syncthreads();
        lx[t] += x0; lx[i1] += x1;
        __syncthreads();
    }
    lx[t] -= lh[t]; lx[t + 256] -= lh[t + 256];
    if (node0 + t       < N) off[node0 + t]       = lo + lx[t];
    if (node0 + t + 256 < N) off[node0 + t + 256] = lo + lx[t + 256];
    lh[t] = 0; lh[t + 256] = 0;
    __syncthreads();
    for (int j = lo + t; j < hi; j += 256) {
        int2 p  = pairs[j];
        int  li = p.y - node0;
        int  r  = atomicAdd(&lh[li], 1);
        csr[lo + lx[li] + r] = p.x;
    }
}

// ---------------- MFMA GEMM (split-bf16, fp32-class accuracy) ----------------
__global__ __launch_bounds__(256) void k_wsplit(const float* __restrict__ W,
                                                unsigned short* __restrict__ wh,
                                                unsigned short* __restrict__ wl,
                                                int K) {
    int idx = blockIdx.x * 256 + threadIdx.x;
    int KT = K >> 5;
    if (idx >= KT * 128) return;
    int lane = idx & 63;
    int nt = (idx >> 6) & 1;
    int kt = idx >> 7;
    int q = lane >> 4, c = lane & 15;
#pragma unroll
    for (int j = 0; j < 8; ++j) {
        int k = kt * 32 + q * 8 + j;
        int n = nt * 16 + c;
        float w = W[k * 32 + n];
        unsigned short hi = f2bf(w);
        wh[idx * 8 + j] = hi;
        wl[idx * 8 + j] = f2bf(w - bf2f(hi));
    }
}

template <int FIN, bool ATT>
__global__ __launch_bounds__(256) void gemm_mfma(
    const float* __restrict__ x,
    const unsigned short* __restrict__ wh, const unsigned short* __restrict__ wl,
    const float* __restrict__ a_s, const float* __restrict__ a_d,
    const float* __restrict__ bias,
    float* __restrict__ h, float* __restrict__ alpha_s,
    float* __restrict__ alpha_d, int N)
{
    constexpr int KT = FIN / 32;
    int lane = threadIdx.x & 63;
    int mt   = blockIdx.x * 4 + (threadIdx.x >> 6);
    int m0   = mt * 16;
    if (m0 >= N) return;
    int q = lane >> 4, c = lane & 15;

    bf8_t Bh[KT][2], Bl[KT][2];
#pragma unroll
    for (int kt = 0; kt < KT; ++kt)
#pragma unroll
        for (int nt = 0; nt < 2; ++nt) {
            Bh[kt][nt] = *(const bf8_t*)(wh + ((size_t)(kt * 2 + nt) * 64 + lane) * 8);
            Bl[kt][nt] = *(const bf8_t*)(wl + ((size_t)(kt * 2 + nt) * 64 + lane) * 8);
        }

    int rowa = m0 + c;
    if (rowa >= N) rowa = N - 1;
    const float* xr = x + (size_t)rowa * FIN;
    bf8_t Ah[KT], Al[KT];
#pragma unroll
    for (int kt = 0; kt < KT; ++kt) {
        f32x4 v0 = *(const f32x4*)(xr + kt * 32 + q * 8);
        f32x4 v1 = *(const f32x4*)(xr + kt * 32 + q * 8 + 4);
#pragma unroll
        for (int j = 0; j < 8; ++j) {
            float f = (j < 4) ? v0[j] : v1[j - 4];
            unsigned short hi = f2bf(f);
            Ah[kt][j] = (short)hi;
            Al[kt][j] = (short)f2bf(f - bf2f(hi));
        }
    }

    f32x4 acc0 = {0.f, 0.f, 0.f, 0.f}, acc1 = {0.f, 0.f, 0.f, 0.f};
#pragma unroll
    for (int kt = 0; kt < KT; ++kt) {
        acc0 = __builtin_amdgcn_mfma_f32_16x16x32_bf16(Ah[kt], Bh[kt][0], acc0, 0, 0, 0);
        acc1 = __builtin_amdgcn_mfma_f32_16x16x32_bf16(Ah[kt], Bh[kt][1], acc1, 0, 0, 0);
        acc0 = __builtin_amdgcn_mfma_f32_16x16x32_bf16(Al[kt], Bh[kt][0], acc0, 0, 0, 0);
        acc1 = __builtin_amdgcn_mfma_f32_16x16x32_bf16(Al[kt], Bh[kt][1], acc1, 0, 0, 0);
        acc0 = __builtin_amdgcn_mfma_f32_16x16x32_bf16(Ah[kt], Bl[kt][0], acc0, 0, 0, 0);
        acc1 = __builtin_amdgcn_mfma_f32_16x16x32_bf16(Ah[kt], Bl[kt][1], acc1, 0, 0, 0);
    }

#pragma unroll
    for (int reg = 0; reg < 4; ++reg) {
        int r = m0 + q * 4 + reg;
        if (r < N) {
            float v0s = acc0[reg], v1s = acc1[reg];
            if (!ATT) { v0s += bias[c]; v1s += bias[c + 16]; }
            h[(size_t)r * 32 + c]      = v0s;
            h[(size_t)r * 32 + 16 + c] = v1s;
        }
    }
    if (ATT) {
        float as0 = a_s[c], as1 = a_s[c + 16];
        float ad0 = a_d[c], ad1 = a_d[c + 16];
#pragma unroll
        for (int reg = 0; reg < 4; ++reg) {
            float ps = acc0[reg] * as0 + acc1[reg] * as1;
            float pd = acc0[reg] * ad0 + acc1[reg] * ad1;
#pragma unroll
            for (int msk = 8; msk >= 1; msk >>= 1) {
                ps += __shfl_xor(ps, msk);
                pd += __shfl_xor(pd, msk);
            }
            int r = m0 + q * 4 + reg;
            if (c == 0 && r < N) {
                alpha_s[r] = ps;
                alpha_d[r] = pd;
            }
        }
    }
}

// ---------------- aggregation ----------------
// One 32-lane group per node, lane k = feature k. Edges processed in chunks
// of 32: lane j loads csr[j] + computes ONE edge weight (dedup'd vs 32x
// redundant), then (c,w) broadcast via width-32 shuffles; 32 h-row gathers
// per chunk are independent (full memory-level parallelism).
__global__ __launch_bounds__(256) void fused_agg(
    const int* __restrict__ csr, const int* __restrict__ off,
    const float* __restrict__ alpha_s, const float* __restrict__ alpha_d,
    const float* __restrict__ h, const float* __restrict__ bias,
    float* __restrict__ out, int N)
{
    int t = blockIdx.x * 256 + threadIdx.x;
    int i = t >> 5, k = t & 31;
    if (i >= N) return;
    int s0 = off[i], s1 = off[i + 1];
    float ad    = alpha_d[i];
    float wself = __expf(leaky(alpha_s[i] + ad));
    float acc   = wself * h[(size_t)i * 32 + k];
    float denp  = 0.0f;
    int j = s0;
    for (; j + 32 <= s1; j += 32) {
        int   c  = csr[j + k];                       // coalesced
        float tc = alpha_s[c] + ad;                  // gather (L2-resident)
        float lw = __expf(fmaxf(tc, 0.f) + NEG_SLOPE * fminf(tc, 0.f));
        denp += lw;
#pragma unroll
        for (int jj = 0; jj < 32; ++jj) {
            int   cj = __shfl(c,  jj, 32);
            float wj = __shfl(lw, jj, 32);
            acc += wj * h[(size_t)cj * 32 + k];
        }
    }
    int rem = s1 - j;
    if (rem > 0) {
        int   c  = csr[j + (k < rem ? k : rem - 1)];
        float tc = alpha_s[c] + ad;
        float lw = (k < rem)
                       ? __expf(fmaxf(tc, 0.f) + NEG_SLOPE * fminf(tc, 0.f))
                       : 0.0f;
        denp += lw;
        // loop bound uniform per 32-lane half; shfl sources always active
        for (int jj = 0; jj < rem; ++jj) {
            int   cj = __shfl(c,  jj, 32);
            float wj = __shfl(lw, jj, 32);
            acc += wj * h[(size_t)cj * 32 + k];
        }
    }
#pragma unroll
    for (int m = 16; m >= 1; m >>= 1) denp += __shfl_xor(denp, m, 32);
    float v = acc / (wself + denp) + bias[k];
    out[(size_t)i * 32 + k] = fmaxf(v, 0.0f);
}

extern "C" void kernel_launch(void* const* d_in, const int* in_sizes, int n_in,
                              void* d_out, int out_size, void* d_ws, size_t ws_size,
                              hipStream_t stream)
{
    const float* x   = (const float*)d_in[0];
    const int*   ei  = (const int*)d_in[1];
    const float* W1  = (const float*)d_in[2];
    const float* a1s = (const float*)d_in[3];
    const float* a1d = (const float*)d_in[4];
    const float* b1  = (const float*)d_in[5];
    const float* W2  = (const float*)d_in[6];
    const float* a2s = (const float*)d_in[7];
    const float* a2d = (const float*)d_in[8];
    const float* b2  = (const float*)d_in[9];
    const float* Wf  = (const float*)d_in[10];
    const float* bf  = (const float*)d_in[11];

    const int N = in_sizes[0] / 128;
    const int E = in_sizes[1] / 2;
    const int* esrc = ei;
    const int* edst = ei + E;
    const int B1 = (N + BK_NODES - 1) >> BK_LOG;

    float* ws = (float*)d_ws;
    float* h1      = ws;
    float* h2      = h1 + (size_t)N * 32;
    float* alpha_s = h2 + (size_t)N * 32;
    float* alpha_d = alpha_s + N;
    int*   off     = (int*)(alpha_d + N);
    int*   csr     = off + (N + 1);
    int*   bcnt    = csr + E;
    int*   bbase   = bcnt + 256;
    int*   bcur    = bbase + 257;
    unsigned short* wfb =
        (unsigned short*)(((uintptr_t)(bcur + 256) + 15) & ~(uintptr_t)15);
    unsigned short* wh1 = wfb;
    unsigned short* wl1 = wh1 + 4096;
    unsigned short* wh2 = wl1 + 4096;
    unsigned short* wl2 = wh2 + 1024;
    unsigned short* whf = wl2 + 1024;
    unsigned short* wlf = whf + 1024;
    int2* pairs = ((size_t)2 * E <= (size_t)64 * N)
                      ? (int2*)h1
                      : (int2*)(wlf + 1024);

    const int nb_node = (N * 32 + 255) / 256;
    const int nb_tile = (E + TILE_E - 1) / TILE_E;
    const int nb_gemm = ((N + 15) / 16 + 3) / 4;

    k_wsplit<<<2, 256, 0, stream>>>(W1, wh1, wl1, 128);
    k_wsplit<<<1, 256, 0, stream>>>(W2, wh2, wl2, 32);
    k_wsplit<<<1, 256, 0, stream>>>(Wf, whf, wlf, 32);

    k_bzero  <<<1, 256, 0, stream>>>(bcnt);
    k_bcount <<<nb_tile, 256, 0, stream>>>(edst, bcnt, E);
    k_bscan  <<<1, 256, 0, stream>>>(bcnt, bbase, bcur, off, N, E);
    k_bplace <<<nb_tile, 256, 0, stream>>>(esrc, edst, bcur, pairs, E);
    k_csr    <<<B1, 256, 0, stream>>>(bbase, pairs, off, csr, N);

    gemm_mfma<128, true><<<nb_gemm, 256, 0, stream>>>(
        x, wh1, wl1, a1s, a1d, nullptr, h1, alpha_s, alpha_d, N);
    fused_agg<<<nb_node, 256, 0, stream>>>(csr, off, alpha_s, alpha_d, h1, b1, h2, N);

    gemm_mfma<32, true><<<nb_gemm, 256, 0, stream>>>(
        h2, wh2, wl2, a2s, a2d, nullptr, h1, alpha_s, alpha_d, N);
    fused_agg<<<nb_node, 256, 0, stream>>>(csr, off, alpha_s, alpha_d, h1, b2, h2, N);

    gemm_mfma<32, false><<<nb_gemm, 256, 0, stream>>>(
        h2, whf, wlf, nullptr, nullptr, bf, (float*)d_out, nullptr, nullptr, N);
}

// Round 7
// 428.303 us; speedup vs baseline: 1.1072x; 1.1072x over previous
//
#include <hip/hip_runtime.h>

#define NEG_SLOPE 0.2f
#define BK_LOG 9
#define BK_NODES (1 << BK_LOG)       // 512 nodes per bucket
#define TILE_EPT 24
#define TILE_E (256 * TILE_EPT)      // 6144 edges per partition tile

typedef __attribute__((ext_vector_type(8))) short bf8_t;   // 8 bf16 (4 VGPRs)
typedef __attribute__((ext_vector_type(4))) float f32x4;

__device__ __forceinline__ float leaky(float v) {
    return fmaxf(v, 0.0f) + NEG_SLOPE * fminf(v, 0.0f);
}

// fp32 -> bf16 (RNE); inputs finite
__device__ __forceinline__ unsigned short f2bf(float f) {
    unsigned u = __float_as_uint(f);
    u += 0x7fffu + ((u >> 16) & 1u);
    return (unsigned short)(u >> 16);
}
__device__ __forceinline__ float bf2f(unsigned short h) {
    return __uint_as_float(((unsigned)h) << 16);
}

__device__ __forceinline__ int scan256_excl(int v, int* tmp) {
    int t = threadIdx.x;
    tmp[t] = v;
    __syncthreads();
    for (int d = 1; d < 256; d <<= 1) {
        int x = (t >= d) ? tmp[t - d] : 0;
        __syncthreads();
        tmp[t] += x;
        __syncthreads();
    }
    int r = tmp[t] - v;
    __syncthreads();
    return r;
}

// ---------------- edge partition (counting sort by dst-bucket) ----------------

__global__ __launch_bounds__(256) void k_bzero(int* __restrict__ bcnt) {
    bcnt[threadIdx.x] = 0;
}

__global__ __launch_bounds__(256) void k_bcount(const int* __restrict__ edst,
                                                int* __restrict__ bcnt, int E) {
    __shared__ int th[256];
    int t = threadIdx.x;
    th[t] = 0;
    __syncthreads();
    int base = blockIdx.x * TILE_E;
#pragma unroll
    for (int k = 0; k < TILE_EPT; ++k) {
        int e = base + t + k * 256;
        if (e < E) atomicAdd(&th[edst[e] >> BK_LOG], 1);
    }
    __syncthreads();
    if (th[t]) atomicAdd(&bcnt[t], th[t]);
}

__global__ __launch_bounds__(256) void k_bscan(const int* __restrict__ bcnt,
                                               int* __restrict__ bbase,
                                               int* __restrict__ bcur,
                                               int* __restrict__ off, int N, int E) {
    __shared__ int tmp[256];
    int t = threadIdx.x;
    int ex = scan256_excl(bcnt[t], tmp);
    bbase[t] = ex;
    bcur[t]  = ex;
    if (t == 0) { bbase[256] = E; off[N] = E; }
}

__global__ __launch_bounds__(256) void k_bplace(const int* __restrict__ esrc,
                                                const int* __restrict__ edst,
                                                int* __restrict__ bcur,
                                                int2* __restrict__ pairs, int E) {
    __shared__ int2 sp[TILE_E];
    __shared__ int th[256], tx[256], rb[256], tmp[256];
    int t = threadIdx.x;
    th[t] = 0;
    __syncthreads();
    int base = blockIdx.x * TILE_E;
    int tot  = min(TILE_E, E - base);
#pragma unroll
    for (int k = 0; k < TILE_EPT; ++k) {
        int e = base + t + k * 256;
        if (e < E) atomicAdd(&th[edst[e] >> BK_LOG], 1);
    }
    __syncthreads();
    int cnt = th[t];
    tx[t] = scan256_excl(cnt, tmp);
    rb[t] = atomicAdd(&bcur[t], cnt);
    th[t] = 0;
    __syncthreads();
#pragma unroll
    for (int k = 0; k < TILE_EPT; ++k) {
        int e = base + t + k * 256;
        if (e < E) {
            int s = esrc[e], d = edst[e];
            int b = d >> BK_LOG;
            int r = atomicAdd(&th[b], 1);
            sp[tx[b] + r] = make_int2(s, d);
        }
    }
    __syncthreads();
    for (int i = t; i < tot; i += 256) {
        int2 p = sp[i];
        int  b = p.y >> BK_LOG;
        pairs[rb[b] + (i - tx[b])] = p;
    }
}

__global__ __launch_bounds__(256) void k_csr(const int* __restrict__ bbase,
                                             const int2* __restrict__ pairs,
                                             int* __restrict__ off,
                                             int* __restrict__ csr, int N) {
    __shared__ int lh[BK_NODES], lx[BK_NODES];
    int b = blockIdx.x, t = threadIdx.x;
    int lo = bbase[b], hi = bbase[b + 1];
    int node0 = b << BK_LOG;
    lh[t] = 0; lh[t + 256] = 0;
    __syncthreads();
    for (int j = lo + t; j < hi; j += 256)
        atomicAdd(&lh[pairs[j].y - node0], 1);
    __syncthreads();
    lx[t] = lh[t]; lx[t + 256] = lh[t + 256];
    __syncthreads();
    for (int d = 1; d < BK_NODES; d <<= 1) {
        int i1 = t + 256;
        int x0 = (t  >= d) ? lx[t  - d] : 0;
        int x1 = (i1 >= d) ? lx[i1 - d] : 0;
        __syncthreads();
        lx[t] += x0; lx[i1] += x1;
        __syncthreads();
    }
    lx[t] -= lh[t]; lx[t + 256] -= lh[t + 256];
    if (node0 + t       < N) off[node0 + t]       = lo + lx[t];
    if (node0 + t + 256 < N) off[node0 + t + 256] = lo + lx[t + 256];
    lh[t] = 0; lh[t + 256] = 0;
    __syncthreads();
    for (int j = lo + t; j < hi; j += 256) {
        int2 p  = pairs[j];
        int  li = p.y - node0;
        int  r  = atomicAdd(&lh[li], 1);
        csr[lo + lx[li] + r] = p.x;
    }
}

// ---------------- MFMA GEMM (split-bf16, fp32-class accuracy) ----------------
__global__ __launch_bounds__(256) void k_wsplit(const float* __restrict__ W,
                                                unsigned short* __restrict__ wh,
                                                unsigned short* __restrict__ wl,
                                                int K) {
    int idx = blockIdx.x * 256 + threadIdx.x;
    int KT = K >> 5;
    if (idx >= KT * 128) return;
    int lane = idx & 63;
    int nt = (idx >> 6) & 1;
    int kt = idx >> 7;
    int q = lane >> 4, c = lane & 15;
#pragma unroll
    for (int j = 0; j < 8; ++j) {
        int k = kt * 32 + q * 8 + j;
        int n = nt * 16 + c;
        float w = W[k * 32 + n];
        unsigned short hi = f2bf(w);
        wh[idx * 8 + j] = hi;
        wl[idx * 8 + j] = f2bf(w - bf2f(hi));
    }
}

template <int FIN, bool ATT>
__global__ __launch_bounds__(256) void gemm_mfma(
    const float* __restrict__ x,
    const unsigned short* __restrict__ wh, const unsigned short* __restrict__ wl,
    const float* __restrict__ a_s, const float* __restrict__ a_d,
    const float* __restrict__ bias,
    float* __restrict__ h, float* __restrict__ alpha_s,
    float* __restrict__ alpha_d, int N)
{
    constexpr int KT = FIN / 32;
    int lane = threadIdx.x & 63;
    int mt   = blockIdx.x * 4 + (threadIdx.x >> 6);
    int m0   = mt * 16;
    if (m0 >= N) return;
    int q = lane >> 4, c = lane & 15;

    bf8_t Bh[KT][2], Bl[KT][2];
#pragma unroll
    for (int kt = 0; kt < KT; ++kt)
#pragma unroll
        for (int nt = 0; nt < 2; ++nt) {
            Bh[kt][nt] = *(const bf8_t*)(wh + ((size_t)(kt * 2 + nt) * 64 + lane) * 8);
            Bl[kt][nt] = *(const bf8_t*)(wl + ((size_t)(kt * 2 + nt) * 64 + lane) * 8);
        }

    int rowa = m0 + c;
    if (rowa >= N) rowa = N - 1;
    const float* xr = x + (size_t)rowa * FIN;
    bf8_t Ah[KT], Al[KT];
#pragma unroll
    for (int kt = 0; kt < KT; ++kt) {
        f32x4 v0 = *(const f32x4*)(xr + kt * 32 + q * 8);
        f32x4 v1 = *(const f32x4*)(xr + kt * 32 + q * 8 + 4);
#pragma unroll
        for (int j = 0; j < 8; ++j) {
            float f = (j < 4) ? v0[j] : v1[j - 4];
            unsigned short hi = f2bf(f);
            Ah[kt][j] = (short)hi;
            Al[kt][j] = (short)f2bf(f - bf2f(hi));
        }
    }

    f32x4 acc0 = {0.f, 0.f, 0.f, 0.f}, acc1 = {0.f, 0.f, 0.f, 0.f};
#pragma unroll
    for (int kt = 0; kt < KT; ++kt) {
        acc0 = __builtin_amdgcn_mfma_f32_16x16x32_bf16(Ah[kt], Bh[kt][0], acc0, 0, 0, 0);
        acc1 = __builtin_amdgcn_mfma_f32_16x16x32_bf16(Ah[kt], Bh[kt][1], acc1, 0, 0, 0);
        acc0 = __builtin_amdgcn_mfma_f32_16x16x32_bf16(Al[kt], Bh[kt][0], acc0, 0, 0, 0);
        acc1 = __builtin_amdgcn_mfma_f32_16x16x32_bf16(Al[kt], Bh[kt][1], acc1, 0, 0, 0);
        acc0 = __builtin_amdgcn_mfma_f32_16x16x32_bf16(Ah[kt], Bl[kt][0], acc0, 0, 0, 0);
        acc1 = __builtin_amdgcn_mfma_f32_16x16x32_bf16(Ah[kt], Bl[kt][1], acc1, 0, 0, 0);
    }

#pragma unroll
    for (int reg = 0; reg < 4; ++reg) {
        int r = m0 + q * 4 + reg;
        if (r < N) {
            float v0s = acc0[reg], v1s = acc1[reg];
            if (!ATT) { v0s += bias[c]; v1s += bias[c + 16]; }
            h[(size_t)r * 32 + c]      = v0s;
            h[(size_t)r * 32 + 16 + c] = v1s;
        }
    }
    if (ATT) {
        float as0 = a_s[c], as1 = a_s[c + 16];
        float ad0 = a_d[c], ad1 = a_d[c + 16];
#pragma unroll
        for (int reg = 0; reg < 4; ++reg) {
            float ps = acc0[reg] * as0 + acc1[reg] * as1;
            float pd = acc0[reg] * ad0 + acc1[reg] * ad1;
#pragma unroll
            for (int msk = 8; msk >= 1; msk >>= 1) {
                ps += __shfl_xor(ps, msk);
                pd += __shfl_xor(pd, msk);
            }
            int r = m0 + q * 4 + reg;
            if (c == 0 && r < N) {
                alpha_s[r] = ps;
                alpha_d[r] = pd;
            }
        }
    }
}

// ---------------- aggregation ----------------

// Per-edge softmax weights + per-node denominator/self-weight.
// One 32-lane group per node; lane-strided over the CSR segment -> one exp
// per edge TOTAL (not per feature-lane), coalesced w[] writes.
__global__ __launch_bounds__(256) void k_edgew(
    const int* __restrict__ csr, const int* __restrict__ off,
    const float* __restrict__ alpha_s, const float* __restrict__ alpha_d,
    float* __restrict__ w, float* __restrict__ den, float* __restrict__ wsf,
    int N)
{
    int t = blockIdx.x * 256 + threadIdx.x;
    int i = t >> 5, k = t & 31;
    if (i >= N) return;
    int s0 = off[i], s1 = off[i + 1];
    float ad = alpha_d[i];
    float dp = 0.0f;
    for (int j = s0 + k; j < s1; j += 32) {
        float tv = alpha_s[csr[j]] + ad;
        float lw = __expf(fmaxf(tv, 0.f) + NEG_SLOPE * fminf(tv, 0.f));
        w[j] = lw;
        dp += lw;
    }
#pragma unroll
    for (int m = 16; m >= 1; m >>= 1) dp += __shfl_xor(dp, m, 32);
    if (k == 0) {
        float tv = alpha_s[i] + ad;
        float ws_ = __expf(fmaxf(tv, 0.f) + NEG_SLOPE * fminf(tv, 0.f));
        den[i] = dp + ws_;
        wsf[i] = ws_;
    }
}

// Pure weighted gather: per edge per lane = 2 broadcast loads + 1 coalesced
// gather + 1 fma. No shuffles on the address path; unroll 8 for MLP.
__global__ __launch_bounds__(256) void fused_agg(
    const int* __restrict__ csr, const int* __restrict__ off,
    const float* __restrict__ w, const float* __restrict__ den,
    const float* __restrict__ wsf,
    const float* __restrict__ h, const float* __restrict__ bias,
    float* __restrict__ out, int N)
{
    int t = blockIdx.x * 256 + threadIdx.x;
    int i = t >> 5, k = t & 31;
    if (i >= N) return;
    int s0 = off[i], s1 = off[i + 1];
    float acc = wsf[i] * h[(size_t)i * 32 + k];
    int j = s0;
    for (; j + 8 <= s1; j += 8) {
        int   c0 = csr[j],     c1 = csr[j + 1], c2 = csr[j + 2], c3 = csr[j + 3];
        int   c4 = csr[j + 4], c5 = csr[j + 5], c6 = csr[j + 6], c7 = csr[j + 7];
        float w0 = w[j],     w1 = w[j + 1], w2 = w[j + 2], w3 = w[j + 3];
        float w4 = w[j + 4], w5 = w[j + 5], w6 = w[j + 6], w7 = w[j + 7];
        acc += w0 * h[(size_t)c0 * 32 + k];
        acc += w1 * h[(size_t)c1 * 32 + k];
        acc += w2 * h[(size_t)c2 * 32 + k];
        acc += w3 * h[(size_t)c3 * 32 + k];
        acc += w4 * h[(size_t)c4 * 32 + k];
        acc += w5 * h[(size_t)c5 * 32 + k];
        acc += w6 * h[(size_t)c6 * 32 + k];
        acc += w7 * h[(size_t)c7 * 32 + k];
    }
    for (; j < s1; ++j)
        acc += w[j] * h[(size_t)csr[j] * 32 + k];
    float v = acc / den[i] + bias[k];
    out[(size_t)i * 32 + k] = fmaxf(v, 0.0f);
}

extern "C" void kernel_launch(void* const* d_in, const int* in_sizes, int n_in,
                              void* d_out, int out_size, void* d_ws, size_t ws_size,
                              hipStream_t stream)
{
    const float* x   = (const float*)d_in[0];
    const int*   ei  = (const int*)d_in[1];
    const float* W1  = (const float*)d_in[2];
    const float* a1s = (const float*)d_in[3];
    const float* a1d = (const float*)d_in[4];
    const float* b1  = (const float*)d_in[5];
    const float* W2  = (const float*)d_in[6];
    const float* a2s = (const float*)d_in[7];
    const float* a2d = (const float*)d_in[8];
    const float* b2  = (const float*)d_in[9];
    const float* Wf  = (const float*)d_in[10];
    const float* bf  = (const float*)d_in[11];

    const int N = in_sizes[0] / 128;
    const int E = in_sizes[1] / 2;
    const int* esrc = ei;
    const int* edst = ei + E;
    const int B1 = (N + BK_NODES - 1) >> BK_LOG;

    // Workspace (4B units): h1 32N | h2 32N | alpha_s N | alpha_d N | den N |
    //   wsf N | off N+1 | csr E | w E | bcnt 256 | bbase 257 | bcur 256 | wfrags
    float* ws = (float*)d_ws;
    float* h1      = ws;
    float* h2      = h1 + (size_t)N * 32;
    float* alpha_s = h2 + (size_t)N * 32;
    float* alpha_d = alpha_s + N;
    float* den     = alpha_d + N;
    float* wsf     = den + N;
    int*   off     = (int*)(wsf + N);
    int*   csr     = off + (N + 1);
    float* w       = (float*)(csr + E);
    int*   bcnt    = (int*)(w + E);
    int*   bbase   = bcnt + 256;
    int*   bcur    = bbase + 257;
    unsigned short* wfb =
        (unsigned short*)(((uintptr_t)(bcur + 256) + 15) & ~(uintptr_t)15);
    unsigned short* wh1 = wfb;
    unsigned short* wl1 = wh1 + 4096;
    unsigned short* wh2 = wl1 + 4096;
    unsigned short* wl2 = wh2 + 1024;
    unsigned short* whf = wl2 + 1024;
    unsigned short* wlf = whf + 1024;
    // pairs (E int2) aliases h1+h2 (build completes before h is live)
    int2* pairs = ((size_t)2 * E <= (size_t)64 * N)
                      ? (int2*)h1
                      : (int2*)(wlf + 1024);

    const int nb_node = (N * 32 + 255) / 256;
    const int nb_tile = (E + TILE_E - 1) / TILE_E;
    const int nb_gemm = ((N + 15) / 16 + 3) / 4;

    k_wsplit<<<2, 256, 0, stream>>>(W1, wh1, wl1, 128);
    k_wsplit<<<1, 256, 0, stream>>>(W2, wh2, wl2, 32);
    k_wsplit<<<1, 256, 0, stream>>>(Wf, whf, wlf, 32);

    k_bzero  <<<1, 256, 0, stream>>>(bcnt);
    k_bcount <<<nb_tile, 256, 0, stream>>>(edst, bcnt, E);
    k_bscan  <<<1, 256, 0, stream>>>(bcnt, bbase, bcur, off, N, E);
    k_bplace <<<nb_tile, 256, 0, stream>>>(esrc, edst, bcur, pairs, E);
    k_csr    <<<B1, 256, 0, stream>>>(bbase, pairs, off, csr, N);

    // ---- layer 1 ----
    gemm_mfma<128, true><<<nb_gemm, 256, 0, stream>>>(
        x, wh1, wl1, a1s, a1d, nullptr, h1, alpha_s, alpha_d, N);
    k_edgew<<<nb_node, 256, 0, stream>>>(csr, off, alpha_s, alpha_d, w, den, wsf, N);
    fused_agg<<<nb_node, 256, 0, stream>>>(csr, off, w, den, wsf, h1, b1, h2, N);

    // ---- layer 2 ----
    gemm_mfma<32, true><<<nb_gemm, 256, 0, stream>>>(
        h2, wh2, wl2, a2s, a2d, nullptr, h1, alpha_s, alpha_d, N);
    k_edgew<<<nb_node, 256, 0, stream>>>(csr, off, alpha_s, alpha_d, w, den, wsf, N);
    fused_agg<<<nb_node, 256, 0, stream>>>(csr, off, w, den, wsf, h1, b2, h2, N);

    // ---- final linear ----
    gemm_mfma<32, false><<<nb_gemm, 256, 0, stream>>>(
        h2, whf, wlf, nullptr, nullptr, bf, (float*)d_out, nullptr, nullptr, N);
}

// Round 8
// 423.932 us; speedup vs baseline: 1.1186x; 1.0103x over previous
//
#include <hip/hip_runtime.h>
#include <hip/hip_fp16.h>

#define NEG_SLOPE 0.2f
#define BK_LOG 9
#define BK_NODES (1 << BK_LOG)       // 512 nodes per bucket; bucket id < 256
#define TILE_EPT 24
#define TILE_E (256 * TILE_EPT)      // 6144 edges per partition tile

typedef __attribute__((ext_vector_type(8))) short bf8_t;   // 8 bf16 (4 VGPRs)
typedef __attribute__((ext_vector_type(4))) float f32x4;

// fp32 -> bf16 (RNE); inputs finite
__device__ __forceinline__ unsigned short f2bf(float f) {
    unsigned u = __float_as_uint(f);
    u += 0x7fffu + ((u >> 16) & 1u);
    return (unsigned short)(u >> 16);
}
__device__ __forceinline__ float bf2f(unsigned short h) {
    return __uint_as_float(((unsigned)h) << 16);
}

__device__ __forceinline__ int scan256_excl(int v, int* tmp) {
    int t = threadIdx.x;
    tmp[t] = v;
    __syncthreads();
    for (int d = 1; d < 256; d <<= 1) {
        int x = (t >= d) ? tmp[t - d] : 0;
        __syncthreads();
        tmp[t] += x;
        __syncthreads();
    }
    int r = tmp[t] - v;
    __syncthreads();
    return r;
}

// ---------------- edge partition (counting sort by dst-bucket) ----------------
// Edge record packed in one uint: (src << BK_LOG) | (dst & (BK_NODES-1)).
// src needs 17 bits (N=100k), dst_lo 9 bits -> 26 bits.

__global__ __launch_bounds__(256) void k_bzero(int* __restrict__ bcnt) {
    bcnt[threadIdx.x] = 0;
}

__global__ __launch_bounds__(256) void k_bcount(const int* __restrict__ edst,
                                                int* __restrict__ bcnt, int E) {
    __shared__ int th[256];
    int t = threadIdx.x;
    th[t] = 0;
    __syncthreads();
    int base = blockIdx.x * TILE_E;
#pragma unroll
    for (int k = 0; k < TILE_EPT; ++k) {
        int e = base + t + k * 256;
        if (e < E) atomicAdd(&th[edst[e] >> BK_LOG], 1);
    }
    __syncthreads();
    if (th[t]) atomicAdd(&bcnt[t], th[t]);
}

__global__ __launch_bounds__(256) void k_bscan(const int* __restrict__ bcnt,
                                               int* __restrict__ bbase,
                                               int* __restrict__ bcur,
                                               int* __restrict__ off, int N, int E) {
    __shared__ int tmp[256];
    int t = threadIdx.x;
    int ex = scan256_excl(bcnt[t], tmp);
    bbase[t] = ex;
    bcur[t]  = ex;
    if (t == 0) { bbase[256] = E; off[N] = E; }
}

__global__ __launch_bounds__(256) void k_bplace(const int* __restrict__ esrc,
                                                const int* __restrict__ edst,
                                                int* __restrict__ bcur,
                                                unsigned* __restrict__ pairs, int E) {
    __shared__ unsigned sp[TILE_E];
    __shared__ unsigned char sb[TILE_E];
    __shared__ int th[256], tx[256], rb[256], tmp[256];
    int t = threadIdx.x;
    th[t] = 0;
    __syncthreads();
    int base = blockIdx.x * TILE_E;
    int tot  = min(TILE_E, E - base);
#pragma unroll
    for (int k = 0; k < TILE_EPT; ++k) {
        int e = base + t + k * 256;
        if (e < E) atomicAdd(&th[edst[e] >> BK_LOG], 1);
    }
    __syncthreads();
    int cnt = th[t];
    tx[t] = scan256_excl(cnt, tmp);
    rb[t] = atomicAdd(&bcur[t], cnt);
    th[t] = 0;
    __syncthreads();
#pragma unroll
    for (int k = 0; k < TILE_EPT; ++k) {
        int e = base + t + k * 256;
        if (e < E) {
            int s = esrc[e], d = edst[e];
            int b = d >> BK_LOG;
            int r = atomicAdd(&th[b], 1);
            int pos = tx[b] + r;
            sp[pos] = ((unsigned)s << BK_LOG) | (unsigned)(d & (BK_NODES - 1));
            sb[pos] = (unsigned char)b;
        }
    }
    __syncthreads();
    for (int i = t; i < tot; i += 256) {
        int b = sb[i];
        pairs[rb[b] + (i - tx[b])] = sp[i];
    }
}

__global__ __launch_bounds__(256) void k_csr(const int* __restrict__ bbase,
                                             const unsigned* __restrict__ pairs,
                                             int* __restrict__ off,
                                             int* __restrict__ csr, int N) {
    __shared__ int lh[BK_NODES], lx[BK_NODES];
    int b = blockIdx.x, t = threadIdx.x;
    int lo = bbase[b], hi = bbase[b + 1];
    int node0 = b << BK_LOG;
    lh[t] = 0; lh[t + 256] = 0;
    __syncthreads();
    for (int j = lo + t; j < hi; j += 256)
        atomicAdd(&lh[pairs[j] & (BK_NODES - 1)], 1);
    __syncthreads();
    lx[t] = lh[t]; lx[t + 256] = lh[t + 256];
    __syncthreads();
    for (int d = 1; d < BK_NODES; d <<= 1) {
        int i1 = t + 256;
        int x0 = (t  >= d) ? lx[t  - d] : 0;
        int x1 = (i1 >= d) ? lx[i1 - d] : 0;
        __syncthreads();
        lx[t] += x0; lx[i1] += x1;
        __syncthreads();
    }
    lx[t] -= lh[t]; lx[t + 256] -= lh[t + 256];
    if (node0 + t       < N) off[node0 + t]       = lo + lx[t];
    if (node0 + t + 256 < N) off[node0 + t + 256] = lo + lx[t + 256];
    lh[t] = 0; lh[t + 256] = 0;
    __syncthreads();
    for (int j = lo + t; j < hi; j += 256) {
        unsigned p  = pairs[j];
        int li = (int)(p & (BK_NODES - 1));
        int r  = atomicAdd(&lh[li], 1);
        csr[lo + lx[li] + r] = (int)(p >> BK_LOG);
    }
}

// ---------------- MFMA GEMM (split-bf16, fp32-class accuracy) ----------------
__global__ __launch_bounds__(256) void k_wsplit(const float* __restrict__ W,
                                                unsigned short* __restrict__ wh,
                                                unsigned short* __restrict__ wl,
                                                int K) {
    int idx = blockIdx.x * 256 + threadIdx.x;
    int KT = K >> 5;
    if (idx >= KT * 128) return;
    int lane = idx & 63;
    int nt = (idx >> 6) & 1;
    int kt = idx >> 7;
    int q = lane >> 4, c = lane & 15;
#pragma unroll
    for (int j = 0; j < 8; ++j) {
        int k = kt * 32 + q * 8 + j;
        int n = nt * 16 + c;
        float w = W[k * 32 + n];
        unsigned short hi = f2bf(w);
        wh[idx * 8 + j] = hi;
        wl[idx * 8 + j] = f2bf(w - bf2f(hi));
    }
}

template <int FIN, bool ATT>
__global__ __launch_bounds__(256) void gemm_mfma(
    const float* __restrict__ x,
    const unsigned short* __restrict__ wh, const unsigned short* __restrict__ wl,
    const float* __restrict__ a_s, const float* __restrict__ a_d,
    const float* __restrict__ bias,
    float* __restrict__ h, __half* __restrict__ h16,
    float* __restrict__ alpha_s, float* __restrict__ alpha_d, int N)
{
    constexpr int KT = FIN / 32;
    int lane = threadIdx.x & 63;
    int mt   = blockIdx.x * 4 + (threadIdx.x >> 6);
    int m0   = mt * 16;
    if (m0 >= N) return;
    int q = lane >> 4, c = lane & 15;

    bf8_t Bh[KT][2], Bl[KT][2];
#pragma unroll
    for (int kt = 0; kt < KT; ++kt)
#pragma unroll
        for (int nt = 0; nt < 2; ++nt) {
            Bh[kt][nt] = *(const bf8_t*)(wh + ((size_t)(kt * 2 + nt) * 64 + lane) * 8);
            Bl[kt][nt] = *(const bf8_t*)(wl + ((size_t)(kt * 2 + nt) * 64 + lane) * 8);
        }

    int rowa = m0 + c;
    if (rowa >= N) rowa = N - 1;
    const float* xr = x + (size_t)rowa * FIN;
    bf8_t Ah[KT], Al[KT];
#pragma unroll
    for (int kt = 0; kt < KT; ++kt) {
        f32x4 v0 = *(const f32x4*)(xr + kt * 32 + q * 8);
        f32x4 v1 = *(const f32x4*)(xr + kt * 32 + q * 8 + 4);
#pragma unroll
        for (int j = 0; j < 8; ++j) {
            float f = (j < 4) ? v0[j] : v1[j - 4];
            unsigned short hi = f2bf(f);
            Ah[kt][j] = (short)hi;
            Al[kt][j] = (short)f2bf(f - bf2f(hi));
        }
    }

    f32x4 acc0 = {0.f, 0.f, 0.f, 0.f}, acc1 = {0.f, 0.f, 0.f, 0.f};
#pragma unroll
    for (int kt = 0; kt < KT; ++kt) {
        acc0 = __builtin_amdgcn_mfma_f32_16x16x32_bf16(Ah[kt], Bh[kt][0], acc0, 0, 0, 0);
        acc1 = __builtin_amdgcn_mfma_f32_16x16x32_bf16(Ah[kt], Bh[kt][1], acc1, 0, 0, 0);
        acc0 = __builtin_amdgcn_mfma_f32_16x16x32_bf16(Al[kt], Bh[kt][0], acc0, 0, 0, 0);
        acc1 = __builtin_amdgcn_mfma_f32_16x16x32_bf16(Al[kt], Bh[kt][1], acc1, 0, 0, 0);
        acc0 = __builtin_amdgcn_mfma_f32_16x16x32_bf16(Ah[kt], Bl[kt][0], acc0, 0, 0, 0);
        acc1 = __builtin_amdgcn_mfma_f32_16x16x32_bf16(Ah[kt], Bl[kt][1], acc1, 0, 0, 0);
    }

#pragma unroll
    for (int reg = 0; reg < 4; ++reg) {
        int r = m0 + q * 4 + reg;
        if (r < N) {
            float v0s = acc0[reg], v1s = acc1[reg];
            if (!ATT) { v0s += bias[c]; v1s += bias[c + 16]; }
            h[(size_t)r * 32 + c]      = v0s;
            h[(size_t)r * 32 + 16 + c] = v1s;
            if (ATT) {   // fp16 copy for the gather phase
                h16[(size_t)r * 32 + c]      = __float2half(v0s);
                h16[(size_t)r * 32 + 16 + c] = __float2half(v1s);
            }
        }
    }
    if (ATT) {
        float as0 = a_s[c], as1 = a_s[c + 16];
        float ad0 = a_d[c], ad1 = a_d[c + 16];
#pragma unroll
        for (int reg = 0; reg < 4; ++reg) {
            float ps = acc0[reg] * as0 + acc1[reg] * as1;
            float pd = acc0[reg] * ad0 + acc1[reg] * ad1;
#pragma unroll
            for (int msk = 8; msk >= 1; msk >>= 1) {
                ps += __shfl_xor(ps, msk);
                pd += __shfl_xor(pd, msk);
            }
            int r = m0 + q * 4 + reg;
            if (c == 0 && r < N) {
                alpha_s[r] = ps;
                alpha_d[r] = pd;
            }
        }
    }
}

// ---------------- aggregation ----------------

// Per-edge softmax weights (fp16) + per-node denominator/self-weight.
__global__ __launch_bounds__(256) void k_edgew(
    const int* __restrict__ csr, const int* __restrict__ off,
    const float* __restrict__ alpha_s, const float* __restrict__ alpha_d,
    __half* __restrict__ w, float* __restrict__ den, float* __restrict__ wsf,
    int N)
{
    int t = blockIdx.x * 256 + threadIdx.x;
    int i = t >> 5, k = t & 31;
    if (i >= N) return;
    int s0 = off[i], s1 = off[i + 1];
    float ad = alpha_d[i];
    float dp = 0.0f;
    for (int j = s0 + k; j < s1; j += 32) {
        float tv = alpha_s[csr[j]] + ad;
        float lw = __expf(fmaxf(tv, 0.f) + NEG_SLOPE * fminf(tv, 0.f));
        w[j] = __float2half(lw);
        dp += lw;
    }
#pragma unroll
    for (int m = 16; m >= 1; m >>= 1) dp += __shfl_xor(dp, m, 32);
    if (k == 0) {
        float tv = alpha_s[i] + ad;
        float ws_ = __expf(fmaxf(tv, 0.f) + NEG_SLOPE * fminf(tv, 0.f));
        den[i] = dp + ws_;
        wsf[i] = ws_;
    }
}

// Pure weighted gather over fp16 rows: 64 B/row instead of 128 B.
__global__ __launch_bounds__(256) void fused_agg(
    const int* __restrict__ csr, const int* __restrict__ off,
    const __half* __restrict__ w, const float* __restrict__ den,
    const float* __restrict__ wsf,
    const float* __restrict__ h, const __half* __restrict__ h16,
    const float* __restrict__ bias, float* __restrict__ out, int N)
{
    int t = blockIdx.x * 256 + threadIdx.x;
    int i = t >> 5, k = t & 31;
    if (i >= N) return;
    int s0 = off[i], s1 = off[i + 1];
    float acc = wsf[i] * h[(size_t)i * 32 + k];   // self term in fp32
    int j = s0;
    for (; j + 8 <= s1; j += 8) {
        int   c0 = csr[j],     c1 = csr[j + 1], c2 = csr[j + 2], c3 = csr[j + 3];
        int   c4 = csr[j + 4], c5 = csr[j + 5], c6 = csr[j + 6], c7 = csr[j + 7];
        float w0 = __half2float(w[j]),     w1 = __half2float(w[j + 1]);
        float w2 = __half2float(w[j + 2]), w3 = __half2float(w[j + 3]);
        float w4 = __half2float(w[j + 4]), w5 = __half2float(w[j + 5]);
        float w6 = __half2float(w[j + 6]), w7 = __half2float(w[j + 7]);
        acc += w0 * __half2float(h16[(size_t)c0 * 32 + k]);
        acc += w1 * __half2float(h16[(size_t)c1 * 32 + k]);
        acc += w2 * __half2float(h16[(size_t)c2 * 32 + k]);
        acc += w3 * __half2float(h16[(size_t)c3 * 32 + k]);
        acc += w4 * __half2float(h16[(size_t)c4 * 32 + k]);
        acc += w5 * __half2float(h16[(size_t)c5 * 32 + k]);
        acc += w6 * __half2float(h16[(size_t)c6 * 32 + k]);
        acc += w7 * __half2float(h16[(size_t)c7 * 32 + k]);
    }
    for (; j < s1; ++j)
        acc += __half2float(w[j]) * __half2float(h16[(size_t)csr[j] * 32 + k]);
    float v = acc / den[i] + bias[k];
    out[(size_t)i * 32 + k] = fmaxf(v, 0.0f);
}

extern "C" void kernel_launch(void* const* d_in, const int* in_sizes, int n_in,
                              void* d_out, int out_size, void* d_ws, size_t ws_size,
                              hipStream_t stream)
{
    const float* x   = (const float*)d_in[0];
    const int*   ei  = (const int*)d_in[1];
    const float* W1  = (const float*)d_in[2];
    const float* a1s = (const float*)d_in[3];
    const float* a1d = (const float*)d_in[4];
    const float* b1  = (const float*)d_in[5];
    const float* W2  = (const float*)d_in[6];
    const float* a2s = (const float*)d_in[7];
    const float* a2d = (const float*)d_in[8];
    const float* b2  = (const float*)d_in[9];
    const float* Wf  = (const float*)d_in[10];
    const float* bf  = (const float*)d_in[11];

    const int N = in_sizes[0] / 128;
    const int E = in_sizes[1] / 2;
    const int* esrc = ei;
    const int* edst = ei + E;
    const int B1 = (N + BK_NODES - 1) >> BK_LOG;

    // Workspace (4B units): h1 32N | h2 32N | alpha_s N | alpha_d N | den N |
    //   wsf N | off N+1 | csr E | w ceil(E/2) | h16 16N | bcnt | bbase | bcur | wfrags
    float* ws = (float*)d_ws;
    float*  h1      = ws;
    float*  h2      = h1 + (size_t)N * 32;
    float*  alpha_s = h2 + (size_t)N * 32;
    float*  alpha_d = alpha_s + N;
    float*  den     = alpha_d + N;
    float*  wsf     = den + N;
    int*    off     = (int*)(wsf + N);
    int*    csr     = off + (N + 1);
    __half* w       = (__half*)(csr + E);
    __half* h16     = (__half*)((float*)w + (E + 1) / 2);
    int*    bcnt    = (int*)(h16 + (size_t)N * 32);
    int*    bbase   = bcnt + 256;
    int*    bcur    = bbase + 257;
    unsigned short* wfb =
        (unsigned short*)(((uintptr_t)(bcur + 256) + 15) & ~(uintptr_t)15);
    unsigned short* wh1 = wfb;
    unsigned short* wl1 = wh1 + 4096;
    unsigned short* wh2 = wl1 + 4096;
    unsigned short* wl2 = wh2 + 1024;
    unsigned short* whf = wl2 + 1024;
    unsigned short* wlf = whf + 1024;
    // pairs (E uints) aliases h1 (build completes before h is live)
    unsigned* pairs = ((size_t)E <= (size_t)32 * N)
                          ? (unsigned*)h1
                          : (unsigned*)(wlf + 1024);

    const int nb_node = (N * 32 + 255) / 256;
    const int nb_tile = (E + TILE_E - 1) / TILE_E;
    const int nb_gemm = ((N + 15) / 16 + 3) / 4;

    k_wsplit<<<2, 256, 0, stream>>>(W1, wh1, wl1, 128);
    k_wsplit<<<1, 256, 0, stream>>>(W2, wh2, wl2, 32);
    k_wsplit<<<1, 256, 0, stream>>>(Wf, whf, wlf, 32);

    k_bzero  <<<1, 256, 0, stream>>>(bcnt);
    k_bcount <<<nb_tile, 256, 0, stream>>>(edst, bcnt, E);
    k_bscan  <<<1, 256, 0, stream>>>(bcnt, bbase, bcur, off, N, E);
    k_bplace <<<nb_tile, 256, 0, stream>>>(esrc, edst, bcur, pairs, E);
    k_csr    <<<B1, 256, 0, stream>>>(bbase, pairs, off, csr, N);

    // ---- layer 1 ----
    gemm_mfma<128, true><<<nb_gemm, 256, 0, stream>>>(
        x, wh1, wl1, a1s, a1d, nullptr, h1, h16, alpha_s, alpha_d, N);
    k_edgew<<<nb_node, 256, 0, stream>>>(csr, off, alpha_s, alpha_d, w, den, wsf, N);
    fused_agg<<<nb_node, 256, 0, stream>>>(csr, off, w, den, wsf, h1, h16, b1, h2, N);

    // ---- layer 2 ----
    gemm_mfma<32, true><<<nb_gemm, 256, 0, stream>>>(
        h2, wh2, wl2, a2s, a2d, nullptr, h1, h16, alpha_s, alpha_d, N);
    k_edgew<<<nb_node, 256, 0, stream>>>(csr, off, alpha_s, alpha_d, w, den, wsf, N);
    fused_agg<<<nb_node, 256, 0, stream>>>(csr, off, w, den, wsf, h1, h16, b2, h2, N);

    // ---- final linear ----
    gemm_mfma<32, false><<<nb_gemm, 256, 0, stream>>>(
        h2, whf, wlf, nullptr, nullptr, bf, (float*)d_out, nullptr, nullptr, nullptr, N);
}